// Round 9
// baseline (393.387 us; speedup 1.0000x reference)
//
#include <hip/hip_runtime.h>

#define IN_CH 512
#define SCAN_BLK 1024

typedef _Float16 f16x8 __attribute__((ext_vector_type(8)));
typedef float f32x4 __attribute__((ext_vector_type(4)));

// async global->LDS, 16B per lane. LDS dest is wave-uniform base + lane*16.
__device__ __forceinline__ void gload_lds16(const void* g, void* l) {
    __builtin_amdgcn_global_load_lds(
        (const __attribute__((address_space(1))) unsigned int*)g,
        (__attribute__((address_space(3))) unsigned int*)l, 16, 0, 0);
}

// ---------------- scan pass 1: per-block sums ----------------
__global__ __launch_bounds__(SCAN_BLK) void k_psum(const int* __restrict__ deg,
                                                   int* __restrict__ bsum, int N) {
    __shared__ int red[SCAN_BLK / 64];
    int i = blockIdx.x * SCAN_BLK + threadIdx.x;
    int v = (i < N) ? deg[i] : 0;
#pragma unroll
    for (int off = 32; off > 0; off >>= 1) v += __shfl_down(v, off);
    if ((threadIdx.x & 63) == 0) red[threadIdx.x >> 6] = v;
    __syncthreads();
    if (threadIdx.x == 0) {
        int s = 0;
#pragma unroll
        for (int u = 0; u < SCAN_BLK / 64; ++u) s += red[u];
        bsum[blockIdx.x] = s;
    }
}

// ---- scan pass 2: per-block scan + block-offset reduce (gridDim <= 64) ----
__global__ __launch_bounds__(SCAN_BLK) void k_write(const int* __restrict__ deg,
                                                    const int* __restrict__ bsum,
                                                    int* __restrict__ rp,
                                                    float* __restrict__ dis,
                                                    int* __restrict__ cursor, int N) {
    __shared__ int sums[SCAN_BLK];
    __shared__ int boff_s, tot_s;
    int t = threadIdx.x;
    if (t < 64) {
        int v = (t < (int)gridDim.x) ? bsum[t] : 0;
        int pre = (t < (int)blockIdx.x) ? v : 0;
        int a = pre, b = v;
#pragma unroll
        for (int off = 32; off > 0; off >>= 1) {
            a += __shfl_down(a, off);
            b += __shfl_down(b, off);
        }
        if (t == 0) { boff_s = a; tot_s = b; }
    }
    int i = blockIdx.x * SCAN_BLK + t;
    int d = (i < N) ? deg[i] : 0;
    sums[t] = d;
    __syncthreads();
    for (int off = 1; off < SCAN_BLK; off <<= 1) {
        int u = (t >= off) ? sums[t - off] : 0;
        __syncthreads();
        sums[t] += u;
        __syncthreads();
    }
    if (i < N) {
        rp[i] = boff_s + sums[t] - d;   // exclusive prefix
        dis[i] = rsqrtf((float)d + 1.0f);
        cursor[i] = 0;
    }
    if (blockIdx.x == gridDim.x - 1 && t == 0) rp[N] = tot_s;
}

// ---------------- CSR fill (src id only) ----------------
__global__ void k_fill(const int* __restrict__ ei, const int* __restrict__ rp,
                       int* __restrict__ cursor, int* __restrict__ csrc,
                       int E, int N) {
    int e = blockIdx.x * blockDim.x + threadIdx.x;
    if (e < E) {
        int s = ei[e];
        int d = ei[E + e];
        if ((unsigned)s < (unsigned)N && (unsigned)d < (unsigned)N) {
            int pos = atomicAdd(&cursor[d], 1);
            csrc[rp[d] + pos] = s;
        }
    }
}

// ---------------- W1 (512x512 fp32) -> W1t (transposed fp16), LDS tile ----------------
__global__ __launch_bounds__(256) void k_cvt_w(const float* __restrict__ W1,
                                               _Float16* __restrict__ W1t) {
    __shared__ float tile[32][33];
    const int bk = blockIdx.x * 32, bn = blockIdx.y * 32;
    const int tx = threadIdx.x & 31, ty = threadIdx.x >> 5;   // 32 x 8
#pragma unroll
    for (int p = 0; p < 4; ++p)
        tile[ty + p * 8][tx] = W1[(size_t)(bk + ty + p * 8) * 512 + bn + tx];
    __syncthreads();
#pragma unroll
    for (int p = 0; p < 4; ++p)
        W1t[(size_t)(bn + ty + p * 8) * 512 + bk + tx] = (_Float16)tile[tx][ty + p * 8];
}

// ------- merged kernel: blocks [0,nwg) = fused-cvt MFMA GEMM, rest = degree count -------
__global__ __launch_bounds__(256) void k_merged(const float* __restrict__ A,
                                                const _Float16* __restrict__ Bt,
                                                _Float16* __restrict__ C,
                                                int Nrows, int nbm,
                                                const int* __restrict__ col,
                                                int* __restrict__ deg, int E, int N) {
    __shared__ __align__(16) _Float16 As[128 * 64];
    __shared__ __align__(16) _Float16 Bs[128 * 64];
    const int nwg = nbm * 4;

    if ((int)blockIdx.x >= nwg) {
        int e = ((int)blockIdx.x - nwg) * 256 + threadIdx.x;
        if (e < E) {
            int d = col[e];
            if ((unsigned)d < (unsigned)N) atomicAdd(&deg[d], 1);
        }
        return;
    }

    // ---- GEMM part: y[m] = cvt16(x[m]) @ W1  (bn-fast + bijective XCD swizzle) ----
    const int t = threadIdx.x;
    const int lane = t & 63, w = t >> 6;
    const int wm = w >> 1, wn = w & 1;

    const int q = nwg >> 3, r = nwg & 7;
    const int xcd = blockIdx.x & 7, within = blockIdx.x >> 3;
    const int wg = (xcd < r ? xcd * (q + 1) : r * (q + 1) + (xcd - r) * q) + within;
    const int bm = (wg >> 2) * 128, bn = (wg & 3) * 128;

    const int rr = lane & 15, kg = lane >> 4;
    const int lrow = lane >> 3, lcol = (lane & 7) * 8;   // B staging: 8 lanes/row
    const int arow = t >> 3, acol = (t & 7) * 8;         // A staging: fp32->fp16

    f32x4 acc[4][4];
#pragma unroll
    for (int i = 0; i < 4; ++i)
#pragma unroll
        for (int j = 0; j < 4; ++j) acc[i][j] = (f32x4)0.0f;

    for (int k0 = 0; k0 < 512; k0 += 64) {
#pragma unroll
        for (int p = 0; p < 4; ++p) {
            const int row = p * 32 + w * 8 + lrow;
            gload_lds16(Bt + (size_t)(bn + row) * 512 + k0 + lcol,
                        Bs + (p * 32 + w * 8) * 64);
        }
#pragma unroll
        for (int p = 0; p < 4; ++p) {
            int grow = bm + p * 32 + arow;
            if (grow >= Nrows) grow = Nrows - 1;
            const float* gp = A + (size_t)grow * 512 + k0 + acol;
            float4 u0 = *(const float4*)gp;
            float4 u1 = *(const float4*)(gp + 4);
            f16x8 o;
            o[0] = (_Float16)u0.x; o[1] = (_Float16)u0.y;
            o[2] = (_Float16)u0.z; o[3] = (_Float16)u0.w;
            o[4] = (_Float16)u1.x; o[5] = (_Float16)u1.y;
            o[6] = (_Float16)u1.z; o[7] = (_Float16)u1.w;
            *(f16x8*)(As + ((p * 32 + arow) * 64 + acol)) = o;
        }
        __syncthreads();
#pragma unroll
        for (int kk = 0; kk < 2; ++kk) {
            f16x8 a[4], b[4];
#pragma unroll
            for (int i = 0; i < 4; ++i)
                a[i] = *(const f16x8*)(As + (wm * 64 + i * 16 + rr) * 64 + kk * 32 + kg * 8);
#pragma unroll
            for (int j = 0; j < 4; ++j)
                b[j] = *(const f16x8*)(Bs + (wn * 64 + j * 16 + rr) * 64 + kk * 32 + kg * 8);
#pragma unroll
            for (int i = 0; i < 4; ++i)
#pragma unroll
                for (int j = 0; j < 4; ++j)
                    acc[i][j] = __builtin_amdgcn_mfma_f32_16x16x32_f16(a[i], b[j], acc[i][j], 0, 0, 0);
        }
        __syncthreads();
    }

#pragma unroll
    for (int i = 0; i < 4; ++i)
#pragma unroll
        for (int j = 0; j < 4; ++j)
#pragma unroll
            for (int reg = 0; reg < 4; ++reg) {
                int m = bm + wm * 64 + i * 16 + kg * 4 + reg;
                int n = bn + wn * 64 + j * 16 + rr;
                C[(size_t)m * 512 + n] = (_Float16)acc[i][j][reg];
            }
}

// ---------------- layer-1 aggregation, CHANNEL-SLICED by XCD ----------------
// slice s = blockIdx & 7 -> dispatch round-robins to XCD s; block touches only
// channels [64s, 64s+64) of y -> per-XCD L2 working set 51 MB -> 6.4 MB.
// one wave per (node, slice); lane l owns channel s*64+l (wave y-load = one 128B line).
// z_part[s][n] = d1 * sum_{c in slice} relu(d1*agg[c]+b1[c])*W2[c]  (no atomics).
__global__ __launch_bounds__(256) void k_agg(const _Float16* __restrict__ y,
                                             const float* __restrict__ dis,
                                             const int* __restrict__ rp,
                                             const int* __restrict__ csrc,
                                             const float* __restrict__ b1,
                                             const float* __restrict__ W2,
                                             float* __restrict__ zp, int N) {
    const int s = blockIdx.x & 7;
    const int n = (blockIdx.x >> 3) * 4 + (threadIdx.x >> 6);
    if (n >= N) return;
    const int l = threadIdx.x & 63;
    const int c = s * 64 + l;

    const float d1 = dis[n];
    float acc = d1 * (float)y[(size_t)n * 512 + c];

    int j = rp[n], jend = rp[n + 1];
    for (; j + 4 <= jend; j += 4) {
        int s0 = csrc[j], s1 = csrc[j + 1], s2 = csrc[j + 2], s3 = csrc[j + 3];
        float w0 = dis[s0], w1 = dis[s1], w2 = dis[s2], w3 = dis[s3];
        float v0 = (float)y[(size_t)s0 * 512 + c];
        float v1 = (float)y[(size_t)s1 * 512 + c];
        float v2 = (float)y[(size_t)s2 * 512 + c];
        float v3 = (float)y[(size_t)s3 * 512 + c];
        acc += (w0 * v0 + w1 * v1) + (w2 * v2 + w3 * v3);
    }
    for (; j < jend; ++j) {
        int s0 = csrc[j];
        acc += dis[s0] * (float)y[(size_t)s0 * 512 + c];
    }

    float h = fmaxf(acc * d1 + b1[c], 0.0f);
    float p = h * W2[c];
#pragma unroll
    for (int off = 32; off > 0; off >>= 1) p += __shfl_down(p, off);
    if (l == 0) zp[(size_t)s * N + n] = d1 * p;
}

// ---------------- reduce the 8 slice partials ----------------
__global__ void k_zred(const float* __restrict__ zp, float* __restrict__ zsum, int N) {
    int n = blockIdx.x * blockDim.x + threadIdx.x;
    if (n >= N) return;
    float a = 0.0f;
#pragma unroll
    for (int s = 0; s < 8; ++s) a += zp[(size_t)s * N + n];
    zsum[n] = a;
}

// ---------------- layer-2 aggregation on prescaled scalars ----------------
__global__ void k_out(const float* __restrict__ z, const float* __restrict__ dis,
                      const int* __restrict__ rp, const int* __restrict__ csrc,
                      const float* __restrict__ b2, float* __restrict__ out, int N) {
    int n = blockIdx.x * blockDim.x + threadIdx.x;
    if (n >= N) return;
    float acc = z[n];
    int j = rp[n], jend = rp[n + 1];
    for (; j + 4 <= jend; j += 4) {
        float a0 = z[csrc[j]];
        float a1 = z[csrc[j + 1]];
        float a2 = z[csrc[j + 2]];
        float a3 = z[csrc[j + 3]];
        acc += (a0 + a1) + (a2 + a3);
    }
    for (; j < jend; ++j) acc += z[csrc[j]];
    out[n] = dis[n] * acc + b2[0];
}

extern "C" void kernel_launch(void* const* d_in, const int* in_sizes, int n_in,
                              void* d_out, int out_size, void* d_ws, size_t ws_size,
                              hipStream_t stream) {
    const float* x  = (const float*)d_in[0];
    const int*   ei = (const int*)d_in[1];
    const float* W1 = (const float*)d_in[2];
    const float* b1 = (const float*)d_in[3];
    const float* W2 = (const float*)d_in[4];
    const float* b2 = (const float*)d_in[5];
    float* out = (float*)d_out;

    const int N = in_sizes[0] / IN_CH;            // 50000
    const int E = in_sizes[1] / 2;                // 800000
    const int nbm = (N + 127) / 128;              // 391
    const int M2 = nbm * 128;                     // 50048
    const int NB = (N + SCAN_BLK - 1) / SCAN_BLK; // 49 (<= 64 for k_write)
    const int DEGB = (E + 255) / 256;             // 3125

    char* ws = (char*)d_ws;
    size_t off = 0;
    auto alloc = [&](size_t bytes) {
        char* p = ws + off;
        off += (bytes + 255) & ~(size_t)255;
        return p;
    };
    _Float16* y   = (_Float16*)alloc((size_t)M2 * 512 * sizeof(_Float16)); // 51.25 MB
    _Float16* W1t = (_Float16*)alloc((size_t)512 * 512 * sizeof(_Float16));
    int*   deg    = (int*)alloc((size_t)N * sizeof(int));
    float* dis    = (float*)alloc((size_t)N * sizeof(float));
    int*   rp     = (int*)alloc((size_t)(N + 1) * sizeof(int));
    int*   cursor = (int*)alloc((size_t)N * sizeof(int));
    int*   csrc   = (int*)alloc((size_t)E * sizeof(int));
    float* zp     = (float*)alloc((size_t)8 * N * sizeof(float));  // 1.6 MB
    float* zsum   = (float*)alloc((size_t)N * sizeof(float));
    int*   bsum   = (int*)alloc((size_t)64 * sizeof(int));

    hipMemsetAsync(deg, 0, (size_t)N * sizeof(int), stream);

    k_cvt_w<<<dim3(16, 16), 256, 0, stream>>>(W1, W1t);
    k_merged<<<nbm * 4 + DEGB, 256, 0, stream>>>(x, W1t, y, N, nbm,
                                                 ei + E, deg, E, N);
    k_psum<<<NB, SCAN_BLK, 0, stream>>>(deg, bsum, N);
    k_write<<<NB, SCAN_BLK, 0, stream>>>(deg, bsum, rp, dis, cursor, N);
    k_fill<<<(E + 255) / 256, 256, 0, stream>>>(ei, rp, cursor, csrc, E, N);
    k_agg<<<((N + 3) / 4) * 8, 256, 0, stream>>>(y, dis, rp, csrc, b1, W2, zp, N);
    k_zred<<<(N + 255) / 256, 256, 0, stream>>>(zp, zsum, N);
    k_out<<<(N + 255) / 256, 256, 0, stream>>>(zsum, dis, rp, csrc, b2, out, N);
}

// Round 10
// 332.701 us; speedup vs baseline: 1.1824x; 1.1824x over previous
//
#include <hip/hip_runtime.h>

#define IN_CH 512
#define SCAN_BLK 1024

typedef _Float16 f16x8 __attribute__((ext_vector_type(8)));
typedef _Float16 f16x2 __attribute__((ext_vector_type(2)));
typedef float f32x4 __attribute__((ext_vector_type(4)));

// async global->LDS, 16B per lane. LDS dest is wave-uniform base + lane*16.
__device__ __forceinline__ void gload_lds16(const void* g, void* l) {
    __builtin_amdgcn_global_load_lds(
        (const __attribute__((address_space(1))) unsigned int*)g,
        (__attribute__((address_space(3))) unsigned int*)l, 16, 0, 0);
}

// ---------------- scan pass 1: per-block sums ----------------
__global__ __launch_bounds__(SCAN_BLK) void k_psum(const int* __restrict__ deg,
                                                   int* __restrict__ bsum, int N) {
    __shared__ int red[SCAN_BLK / 64];
    int i = blockIdx.x * SCAN_BLK + threadIdx.x;
    int v = (i < N) ? deg[i] : 0;
#pragma unroll
    for (int off = 32; off > 0; off >>= 1) v += __shfl_down(v, off);
    if ((threadIdx.x & 63) == 0) red[threadIdx.x >> 6] = v;
    __syncthreads();
    if (threadIdx.x == 0) {
        int s = 0;
#pragma unroll
        for (int u = 0; u < SCAN_BLK / 64; ++u) s += red[u];
        bsum[blockIdx.x] = s;
    }
}

// ---- scan pass 2: per-block scan + block-offset reduce (gridDim <= 64) ----
__global__ __launch_bounds__(SCAN_BLK) void k_write(const int* __restrict__ deg,
                                                    const int* __restrict__ bsum,
                                                    int* __restrict__ rp,
                                                    float* __restrict__ dis,
                                                    int* __restrict__ cursor, int N) {
    __shared__ int sums[SCAN_BLK];
    __shared__ int boff_s, tot_s;
    int t = threadIdx.x;
    if (t < 64) {
        int v = (t < (int)gridDim.x) ? bsum[t] : 0;
        int pre = (t < (int)blockIdx.x) ? v : 0;
        int a = pre, b = v;
#pragma unroll
        for (int off = 32; off > 0; off >>= 1) {
            a += __shfl_down(a, off);
            b += __shfl_down(b, off);
        }
        if (t == 0) { boff_s = a; tot_s = b; }
    }
    int i = blockIdx.x * SCAN_BLK + t;
    int d = (i < N) ? deg[i] : 0;
    sums[t] = d;
    __syncthreads();
    for (int off = 1; off < SCAN_BLK; off <<= 1) {
        int u = (t >= off) ? sums[t - off] : 0;
        __syncthreads();
        sums[t] += u;
        __syncthreads();
    }
    if (i < N) {
        rp[i] = boff_s + sums[t] - d;   // exclusive prefix
        dis[i] = rsqrtf((float)d + 1.0f);
        cursor[i] = 0;
    }
    if (blockIdx.x == gridDim.x - 1 && t == 0) rp[N] = tot_s;
}

// ---------------- CSR fill (src id only) ----------------
__global__ void k_fill(const int* __restrict__ ei, const int* __restrict__ rp,
                       int* __restrict__ cursor, int* __restrict__ csrc,
                       int E, int N) {
    int e = blockIdx.x * blockDim.x + threadIdx.x;
    if (e < E) {
        int s = ei[e];
        int d = ei[E + e];
        if ((unsigned)s < (unsigned)N && (unsigned)d < (unsigned)N) {
            int pos = atomicAdd(&cursor[d], 1);
            csrc[rp[d] + pos] = s;
        }
    }
}

// ---------------- W1 (512x512 fp32) -> W1t (transposed fp16), LDS tile ----------------
__global__ __launch_bounds__(256) void k_cvt_w(const float* __restrict__ W1,
                                               _Float16* __restrict__ W1t) {
    __shared__ float tile[32][33];
    const int bk = blockIdx.x * 32, bn = blockIdx.y * 32;
    const int tx = threadIdx.x & 31, ty = threadIdx.x >> 5;   // 32 x 8
#pragma unroll
    for (int p = 0; p < 4; ++p)
        tile[ty + p * 8][tx] = W1[(size_t)(bk + ty + p * 8) * 512 + bn + tx];
    __syncthreads();
#pragma unroll
    for (int p = 0; p < 4; ++p)
        W1t[(size_t)(bn + ty + p * 8) * 512 + bk + tx] = (_Float16)tile[tx][ty + p * 8];
}

// ------- merged kernel: blocks [0,nwg) = fused-cvt MFMA GEMM, rest = degree count -------
__global__ __launch_bounds__(256) void k_merged(const float* __restrict__ A,
                                                const _Float16* __restrict__ Bt,
                                                _Float16* __restrict__ C,
                                                int Nrows, int nbm,
                                                const int* __restrict__ col,
                                                int* __restrict__ deg, int E, int N) {
    __shared__ __align__(16) _Float16 As[128 * 64];
    __shared__ __align__(16) _Float16 Bs[128 * 64];
    const int nwg = nbm * 4;

    if ((int)blockIdx.x >= nwg) {
        int e = ((int)blockIdx.x - nwg) * 256 + threadIdx.x;
        if (e < E) {
            int d = col[e];
            if ((unsigned)d < (unsigned)N) atomicAdd(&deg[d], 1);
        }
        return;
    }

    // ---- GEMM part: y[m] = cvt16(x[m]) @ W1  (bn-fast + bijective XCD swizzle) ----
    const int t = threadIdx.x;
    const int lane = t & 63, w = t >> 6;
    const int wm = w >> 1, wn = w & 1;

    const int q = nwg >> 3, r = nwg & 7;
    const int xcd = blockIdx.x & 7, within = blockIdx.x >> 3;
    const int wg = (xcd < r ? xcd * (q + 1) : r * (q + 1) + (xcd - r) * q) + within;
    const int bm = (wg >> 2) * 128, bn = (wg & 3) * 128;

    const int rr = lane & 15, kg = lane >> 4;
    const int lrow = lane >> 3, lcol = (lane & 7) * 8;   // B staging: 8 lanes/row
    const int arow = t >> 3, acol = (t & 7) * 8;         // A staging: fp32->fp16

    f32x4 acc[4][4];
#pragma unroll
    for (int i = 0; i < 4; ++i)
#pragma unroll
        for (int j = 0; j < 4; ++j) acc[i][j] = (f32x4)0.0f;

    for (int k0 = 0; k0 < 512; k0 += 64) {
#pragma unroll
        for (int p = 0; p < 4; ++p) {
            const int row = p * 32 + w * 8 + lrow;
            gload_lds16(Bt + (size_t)(bn + row) * 512 + k0 + lcol,
                        Bs + (p * 32 + w * 8) * 64);
        }
#pragma unroll
        for (int p = 0; p < 4; ++p) {
            int grow = bm + p * 32 + arow;
            if (grow >= Nrows) grow = Nrows - 1;
            const float* gp = A + (size_t)grow * 512 + k0 + acol;
            float4 u0 = *(const float4*)gp;
            float4 u1 = *(const float4*)(gp + 4);
            f16x8 o;
            o[0] = (_Float16)u0.x; o[1] = (_Float16)u0.y;
            o[2] = (_Float16)u0.z; o[3] = (_Float16)u0.w;
            o[4] = (_Float16)u1.x; o[5] = (_Float16)u1.y;
            o[6] = (_Float16)u1.z; o[7] = (_Float16)u1.w;
            *(f16x8*)(As + ((p * 32 + arow) * 64 + acol)) = o;
        }
        __syncthreads();
#pragma unroll
        for (int kk = 0; kk < 2; ++kk) {
            f16x8 a[4], b[4];
#pragma unroll
            for (int i = 0; i < 4; ++i)
                a[i] = *(const f16x8*)(As + (wm * 64 + i * 16 + rr) * 64 + kk * 32 + kg * 8);
#pragma unroll
            for (int j = 0; j < 4; ++j)
                b[j] = *(const f16x8*)(Bs + (wn * 64 + j * 16 + rr) * 64 + kk * 32 + kg * 8);
#pragma unroll
            for (int i = 0; i < 4; ++i)
#pragma unroll
                for (int j = 0; j < 4; ++j)
                    acc[i][j] = __builtin_amdgcn_mfma_f32_16x16x32_f16(a[i], b[j], acc[i][j], 0, 0, 0);
        }
        __syncthreads();
    }

#pragma unroll
    for (int i = 0; i < 4; ++i)
#pragma unroll
        for (int j = 0; j < 4; ++j)
#pragma unroll
            for (int reg = 0; reg < 4; ++reg) {
                int m = bm + wm * 64 + i * 16 + kg * 4 + reg;
                int n = bn + wn * 64 + j * 16 + rr;
                C[(size_t)m * 512 + n] = (_Float16)acc[i][j][reg];
            }
}

// ---------------- layer-1 aggregation, channel-sliced (W=128, 4 slices) ----------------
// Round-9 lesson: W=64 + unroll-4 halved FETCH (locality works) but cut per-wave
// in-flight bytes 16x -> latency-bound. This round: W=128 (lane owns 2 ch, f16x2),
// unroll 16 -> 64B/lane in flight (8x round-9). Per-XCD slice ws = 12.8 MB.
__global__ __launch_bounds__(256) void k_agg(const _Float16* __restrict__ y,
                                             const float* __restrict__ dis,
                                             const int* __restrict__ rp,
                                             const int* __restrict__ csrc,
                                             const float* __restrict__ b1,
                                             const float* __restrict__ W2,
                                             float* __restrict__ zp, int N) {
    const int s = blockIdx.x & 3;
    const int n = (blockIdx.x >> 2) * 4 + (threadIdx.x >> 6);
    if (n >= N) return;
    const int l = threadIdx.x & 63;
    const int c = s * 128 + l * 2;

    const float d1 = dis[n];
    f16x2 self = *(const f16x2*)(y + (size_t)n * 512 + c);
    float a0 = d1 * (float)self[0];
    float a1 = d1 * (float)self[1];

    int j = rp[n], jend = rp[n + 1];
    for (; j + 16 <= jend; j += 16) {
        int src[16];
#pragma unroll
        for (int u = 0; u < 16; ++u) src[u] = csrc[j + u];
        f16x2 v[16];
#pragma unroll
        for (int u = 0; u < 16; ++u)
            v[u] = *(const f16x2*)(y + (size_t)src[u] * 512 + c);
        float wt[16];
#pragma unroll
        for (int u = 0; u < 16; ++u) wt[u] = dis[src[u]];
#pragma unroll
        for (int u = 0; u < 16; ++u) {
            a0 += wt[u] * (float)v[u][0];
            a1 += wt[u] * (float)v[u][1];
        }
    }
    for (; j + 4 <= jend; j += 4) {
        int s0 = csrc[j], s1 = csrc[j + 1], s2 = csrc[j + 2], s3 = csrc[j + 3];
        f16x2 v0 = *(const f16x2*)(y + (size_t)s0 * 512 + c);
        f16x2 v1 = *(const f16x2*)(y + (size_t)s1 * 512 + c);
        f16x2 v2 = *(const f16x2*)(y + (size_t)s2 * 512 + c);
        f16x2 v3 = *(const f16x2*)(y + (size_t)s3 * 512 + c);
        float w0 = dis[s0], w1 = dis[s1], w2 = dis[s2], w3 = dis[s3];
        a0 += (w0 * (float)v0[0] + w1 * (float)v1[0]) + (w2 * (float)v2[0] + w3 * (float)v3[0]);
        a1 += (w0 * (float)v0[1] + w1 * (float)v1[1]) + (w2 * (float)v2[1] + w3 * (float)v3[1]);
    }
    for (; j < jend; ++j) {
        int s0 = csrc[j];
        float w0 = dis[s0];
        f16x2 v0 = *(const f16x2*)(y + (size_t)s0 * 512 + c);
        a0 += w0 * (float)v0[0];
        a1 += w0 * (float)v0[1];
    }

    float h0 = fmaxf(a0 * d1 + b1[c], 0.0f);
    float h1 = fmaxf(a1 * d1 + b1[c + 1], 0.0f);
    float p = h0 * W2[c] + h1 * W2[c + 1];
#pragma unroll
    for (int off = 32; off > 0; off >>= 1) p += __shfl_down(p, off);
    if (l == 0) zp[(size_t)s * N + n] = d1 * p;
}

// ---------------- reduce the 4 slice partials ----------------
__global__ void k_zred(const float* __restrict__ zp, float* __restrict__ zsum, int N) {
    int n = blockIdx.x * blockDim.x + threadIdx.x;
    if (n >= N) return;
    float a = 0.0f;
#pragma unroll
    for (int s = 0; s < 4; ++s) a += zp[(size_t)s * N + n];
    zsum[n] = a;
}

// ---------------- layer-2 aggregation on prescaled scalars ----------------
__global__ void k_out(const float* __restrict__ z, const float* __restrict__ dis,
                      const int* __restrict__ rp, const int* __restrict__ csrc,
                      const float* __restrict__ b2, float* __restrict__ out, int N) {
    int n = blockIdx.x * blockDim.x + threadIdx.x;
    if (n >= N) return;
    float acc = z[n];
    int j = rp[n], jend = rp[n + 1];
    for (; j + 4 <= jend; j += 4) {
        float a0 = z[csrc[j]];
        float a1 = z[csrc[j + 1]];
        float a2 = z[csrc[j + 2]];
        float a3 = z[csrc[j + 3]];
        acc += (a0 + a1) + (a2 + a3);
    }
    for (; j < jend; ++j) acc += z[csrc[j]];
    out[n] = dis[n] * acc + b2[0];
}

extern "C" void kernel_launch(void* const* d_in, const int* in_sizes, int n_in,
                              void* d_out, int out_size, void* d_ws, size_t ws_size,
                              hipStream_t stream) {
    const float* x  = (const float*)d_in[0];
    const int*   ei = (const int*)d_in[1];
    const float* W1 = (const float*)d_in[2];
    const float* b1 = (const float*)d_in[3];
    const float* W2 = (const float*)d_in[4];
    const float* b2 = (const float*)d_in[5];
    float* out = (float*)d_out;

    const int N = in_sizes[0] / IN_CH;            // 50000
    const int E = in_sizes[1] / 2;                // 800000
    const int nbm = (N + 127) / 128;              // 391
    const int M2 = nbm * 128;                     // 50048
    const int NB = (N + SCAN_BLK - 1) / SCAN_BLK; // 49 (<= 64 for k_write)
    const int DEGB = (E + 255) / 256;             // 3125

    char* ws = (char*)d_ws;
    size_t off = 0;
    auto alloc = [&](size_t bytes) {
        char* p = ws + off;
        off += (bytes + 255) & ~(size_t)255;
        return p;
    };
    _Float16* y   = (_Float16*)alloc((size_t)M2 * 512 * sizeof(_Float16)); // 51.25 MB
    _Float16* W1t = (_Float16*)alloc((size_t)512 * 512 * sizeof(_Float16));
    int*   deg    = (int*)alloc((size_t)N * sizeof(int));
    float* dis    = (float*)alloc((size_t)N * sizeof(float));
    int*   rp     = (int*)alloc((size_t)(N + 1) * sizeof(int));
    int*   cursor = (int*)alloc((size_t)N * sizeof(int));
    int*   csrc   = (int*)alloc((size_t)E * sizeof(int));
    float* zp     = (float*)alloc((size_t)4 * N * sizeof(float));  // 0.8 MB
    float* zsum   = (float*)alloc((size_t)N * sizeof(float));
    int*   bsum   = (int*)alloc((size_t)64 * sizeof(int));

    hipMemsetAsync(deg, 0, (size_t)N * sizeof(int), stream);

    k_cvt_w<<<dim3(16, 16), 256, 0, stream>>>(W1, W1t);
    k_merged<<<nbm * 4 + DEGB, 256, 0, stream>>>(x, W1t, y, N, nbm,
                                                 ei + E, deg, E, N);
    k_psum<<<NB, SCAN_BLK, 0, stream>>>(deg, bsum, N);
    k_write<<<NB, SCAN_BLK, 0, stream>>>(deg, bsum, rp, dis, cursor, N);
    k_fill<<<(E + 255) / 256, 256, 0, stream>>>(ei, rp, cursor, csrc, E, N);
    k_agg<<<((N + 3) / 4) * 4, 256, 0, stream>>>(y, dis, rp, csrc, b1, W2, zp, N);
    k_zred<<<(N + 255) / 256, 256, 0, stream>>>(zp, zsum, N);
    k_out<<<(N + 255) / 256, 256, 0, stream>>>(zsum, dis, rp, csrc, b2, out, N);
}

// Round 11
// 263.696 us; speedup vs baseline: 1.4918x; 1.2617x over previous
//
#include <hip/hip_runtime.h>

#define IN_CH 512
#define SCAN_BLK 1024

typedef _Float16 f16x8 __attribute__((ext_vector_type(8)));
typedef float f32x4 __attribute__((ext_vector_type(4)));

// async global->LDS, 16B per lane. LDS dest is wave-uniform base + lane*16.
__device__ __forceinline__ void gload_lds16(const void* g, void* l) {
    __builtin_amdgcn_global_load_lds(
        (const __attribute__((address_space(1))) unsigned int*)g,
        (__attribute__((address_space(3))) unsigned int*)l, 16, 0, 0);
}

// ------- merged1: blocks [0,256) = W1 transpose+cvt, rest = degree count -------
__global__ __launch_bounds__(256) void k_merged1(const float* __restrict__ W1,
                                                 _Float16* __restrict__ W1t,
                                                 const int* __restrict__ col,
                                                 int* __restrict__ deg, int E, int N) {
    __shared__ float tile[32][33];
    if ((int)blockIdx.x >= 256) {
        int e = ((int)blockIdx.x - 256) * 256 + threadIdx.x;
        if (e < E) {
            int d = col[e];
            if ((unsigned)d < (unsigned)N) atomicAdd(&deg[d], 1);
        }
        return;
    }
    const int bk = (blockIdx.x & 15) * 32, bn = (blockIdx.x >> 4) * 32;
    const int tx = threadIdx.x & 31, ty = threadIdx.x >> 5;   // 32 x 8
#pragma unroll
    for (int p = 0; p < 4; ++p)
        tile[ty + p * 8][tx] = W1[(size_t)(bk + ty + p * 8) * 512 + bn + tx];
    __syncthreads();
#pragma unroll
    for (int p = 0; p < 4; ++p)
        W1t[(size_t)(bn + ty + p * 8) * 512 + bk + tx] = (_Float16)tile[tx][ty + p * 8];
}

// ---------------- scan pass 1: per-block sums ----------------
__global__ __launch_bounds__(SCAN_BLK) void k_psum(const int* __restrict__ deg,
                                                   int* __restrict__ bsum, int N) {
    __shared__ int red[SCAN_BLK / 64];
    int i = blockIdx.x * SCAN_BLK + threadIdx.x;
    int v = (i < N) ? deg[i] : 0;
#pragma unroll
    for (int off = 32; off > 0; off >>= 1) v += __shfl_down(v, off);
    if ((threadIdx.x & 63) == 0) red[threadIdx.x >> 6] = v;
    __syncthreads();
    if (threadIdx.x == 0) {
        int s = 0;
#pragma unroll
        for (int u = 0; u < SCAN_BLK / 64; ++u) s += red[u];
        bsum[blockIdx.x] = s;
    }
}

// ---- scan pass 2: per-block scan + block-offset reduce (gridDim <= 64) ----
__global__ __launch_bounds__(SCAN_BLK) void k_write(const int* __restrict__ deg,
                                                    const int* __restrict__ bsum,
                                                    int* __restrict__ rp,
                                                    float* __restrict__ dis,
                                                    int* __restrict__ cursor, int N) {
    __shared__ int sums[SCAN_BLK];
    __shared__ int boff_s, tot_s;
    int t = threadIdx.x;
    if (t < 64) {
        int v = (t < (int)gridDim.x) ? bsum[t] : 0;
        int pre = (t < (int)blockIdx.x) ? v : 0;
        int a = pre, b = v;
#pragma unroll
        for (int off = 32; off > 0; off >>= 1) {
            a += __shfl_down(a, off);
            b += __shfl_down(b, off);
        }
        if (t == 0) { boff_s = a; tot_s = b; }
    }
    int i = blockIdx.x * SCAN_BLK + t;
    int d = (i < N) ? deg[i] : 0;
    sums[t] = d;
    __syncthreads();
    for (int off = 1; off < SCAN_BLK; off <<= 1) {
        int u = (t >= off) ? sums[t - off] : 0;
        __syncthreads();
        sums[t] += u;
        __syncthreads();
    }
    if (i < N) {
        rp[i] = boff_s + sums[t] - d;   // exclusive prefix
        dis[i] = rsqrtf((float)d + 1.0f);
        cursor[i] = 0;
    }
    if (blockIdx.x == gridDim.x - 1 && t == 0) rp[N] = tot_s;
}

// ------- merged2: blocks [0,fillb) = CSR fill, [fillb, fillb+nwg) = MFMA GEMM -------
// fill (random atomics, latency-bound) overlaps with gemm (MFMA/LDS-bound).
// fillb padded to %8==0 so gemm's XCD swizzle stays aligned (bid&7 == g&7).
__global__ __launch_bounds__(256) void k_merged2(const float* __restrict__ A,
                                                 const _Float16* __restrict__ Bt,
                                                 _Float16* __restrict__ C,
                                                 int Nrows, int nbm, int fillb,
                                                 const int* __restrict__ ei,
                                                 const int* __restrict__ rp,
                                                 int* __restrict__ cursor,
                                                 int* __restrict__ csrc,
                                                 int E, int N) {
    __shared__ __align__(16) _Float16 As[128 * 64];
    __shared__ __align__(16) _Float16 Bs[128 * 64];

    if ((int)blockIdx.x < fillb) {
        int e = (int)blockIdx.x * 256 + threadIdx.x;
        if (e < E) {
            int s = ei[e];
            int d = ei[E + e];
            if ((unsigned)s < (unsigned)N && (unsigned)d < (unsigned)N) {
                int pos = atomicAdd(&cursor[d], 1);
                csrc[rp[d] + pos] = s;
            }
        }
        return;
    }

    // ---- GEMM part: y[m] = cvt16(x[m]) @ W1  (bn-fast + bijective XCD swizzle) ----
    const int g = (int)blockIdx.x - fillb;
    const int nwg = nbm * 4;
    const int t = threadIdx.x;
    const int lane = t & 63, w = t >> 6;
    const int wm = w >> 1, wn = w & 1;

    const int q = nwg >> 3, r = nwg & 7;
    const int xcd = g & 7, within = g >> 3;
    const int wg = (xcd < r ? xcd * (q + 1) : r * (q + 1) + (xcd - r) * q) + within;
    const int bm = (wg >> 2) * 128, bn = (wg & 3) * 128;

    const int rr = lane & 15, kg = lane >> 4;
    const int lrow = lane >> 3, lcol = (lane & 7) * 8;   // B staging: 8 lanes/row
    const int arow = t >> 3, acol = (t & 7) * 8;         // A staging: fp32->fp16

    f32x4 acc[4][4];
#pragma unroll
    for (int i = 0; i < 4; ++i)
#pragma unroll
        for (int j = 0; j < 4; ++j) acc[i][j] = (f32x4)0.0f;

    for (int k0 = 0; k0 < 512; k0 += 64) {
#pragma unroll
        for (int p = 0; p < 4; ++p) {
            const int row = p * 32 + w * 8 + lrow;
            gload_lds16(Bt + (size_t)(bn + row) * 512 + k0 + lcol,
                        Bs + (p * 32 + w * 8) * 64);
        }
#pragma unroll
        for (int p = 0; p < 4; ++p) {
            int grow = bm + p * 32 + arow;
            if (grow >= Nrows) grow = Nrows - 1;
            const float* gp = A + (size_t)grow * 512 + k0 + acol;
            float4 u0 = *(const float4*)gp;
            float4 u1 = *(const float4*)(gp + 4);
            f16x8 o;
            o[0] = (_Float16)u0.x; o[1] = (_Float16)u0.y;
            o[2] = (_Float16)u0.z; o[3] = (_Float16)u0.w;
            o[4] = (_Float16)u1.x; o[5] = (_Float16)u1.y;
            o[6] = (_Float16)u1.z; o[7] = (_Float16)u1.w;
            *(f16x8*)(As + ((p * 32 + arow) * 64 + acol)) = o;
        }
        __syncthreads();
#pragma unroll
        for (int kk = 0; kk < 2; ++kk) {
            f16x8 a[4], b[4];
#pragma unroll
            for (int i = 0; i < 4; ++i)
                a[i] = *(const f16x8*)(As + (wm * 64 + i * 16 + rr) * 64 + kk * 32 + kg * 8);
#pragma unroll
            for (int j = 0; j < 4; ++j)
                b[j] = *(const f16x8*)(Bs + (wn * 64 + j * 16 + rr) * 64 + kk * 32 + kg * 8);
#pragma unroll
            for (int i = 0; i < 4; ++i)
#pragma unroll
                for (int j = 0; j < 4; ++j)
                    acc[i][j] = __builtin_amdgcn_mfma_f32_16x16x32_f16(a[i], b[j], acc[i][j], 0, 0, 0);
        }
        __syncthreads();
    }

#pragma unroll
    for (int i = 0; i < 4; ++i)
#pragma unroll
        for (int j = 0; j < 4; ++j)
#pragma unroll
            for (int reg = 0; reg < 4; ++reg) {
                int m = bm + wm * 64 + i * 16 + kg * 4 + reg;
                int n = bn + wn * 64 + j * 16 + rr;
                C[(size_t)m * 512 + n] = (_Float16)acc[i][j][reg];
            }
}

// ---------------- layer-1 aggregation (round-8 form: full width, unroll 8) ----------------
// R9/R10 lesson: channel-slicing cuts FETCH but time tracks slice count (per-edge
// uniform-load redundancy), and R8 is genuinely BW-bound at ~3.6 TB/s -> this is the floor.
__global__ __launch_bounds__(256) void k_agg(const _Float16* __restrict__ y,
                                             const float* __restrict__ dis,
                                             const int* __restrict__ rp,
                                             const int* __restrict__ csrc,
                                             const float* __restrict__ b1,
                                             const float* __restrict__ W2,
                                             float* __restrict__ z, int N) {
    const int n = blockIdx.x * 4 + (threadIdx.x >> 6);
    if (n >= N) return;
    const int l = threadIdx.x & 63;

    const float d1 = dis[n];
    f16x8 self = *(const f16x8*)(y + (size_t)n * 512 + l * 8);
    float acc[8];
#pragma unroll
    for (int c = 0; c < 8; ++c) acc[c] = d1 * (float)self[c];

    int j = rp[n], jend = rp[n + 1];
    for (; j + 8 <= jend; j += 8) {
        int s[8]; float wt[8]; f16x8 v[8];
#pragma unroll
        for (int u = 0; u < 8; ++u) s[u] = csrc[j + u];
#pragma unroll
        for (int u = 0; u < 8; ++u) wt[u] = dis[s[u]];
#pragma unroll
        for (int u = 0; u < 8; ++u)
            v[u] = *(const f16x8*)(y + (size_t)s[u] * 512 + l * 8);
#pragma unroll
        for (int u = 0; u < 8; ++u)
#pragma unroll
            for (int c = 0; c < 8; ++c) acc[c] += wt[u] * (float)v[u][c];
    }
    for (; j + 2 <= jend; j += 2) {
        int s0 = csrc[j], s1 = csrc[j + 1];
        float w0 = dis[s0], w1 = dis[s1];
        f16x8 v0 = *(const f16x8*)(y + (size_t)s0 * 512 + l * 8);
        f16x8 v1 = *(const f16x8*)(y + (size_t)s1 * 512 + l * 8);
#pragma unroll
        for (int c = 0; c < 8; ++c) acc[c] += w0 * (float)v0[c] + w1 * (float)v1[c];
    }
    if (j < jend) {
        int s0 = csrc[j];
        float w0 = dis[s0];
        f16x8 v0 = *(const f16x8*)(y + (size_t)s0 * 512 + l * 8);
#pragma unroll
        for (int c = 0; c < 8; ++c) acc[c] += w0 * (float)v0[c];
    }

    float4 bb0 = *(const float4*)(b1 + l * 8);
    float4 bb1 = *(const float4*)(b1 + l * 8 + 4);
    float4 w20 = *(const float4*)(W2 + l * 8);
    float4 w21 = *(const float4*)(W2 + l * 8 + 4);
    float bbv[8] = {bb0.x, bb0.y, bb0.z, bb0.w, bb1.x, bb1.y, bb1.z, bb1.w};
    float w2v[8] = {w20.x, w20.y, w20.z, w20.w, w21.x, w21.y, w21.z, w21.w};
    float p = 0.0f;
#pragma unroll
    for (int c = 0; c < 8; ++c) {
        float h = fmaxf(acc[c] * d1 + bbv[c], 0.0f);
        p += h * w2v[c];
    }
#pragma unroll
    for (int off = 32; off > 0; off >>= 1) p += __shfl_down(p, off);
    if (l == 0) z[n] = d1 * p;
}

// ---------------- layer-2 aggregation on prescaled scalars ----------------
__global__ void k_out(const float* __restrict__ z, const float* __restrict__ dis,
                      const int* __restrict__ rp, const int* __restrict__ csrc,
                      const float* __restrict__ b2, float* __restrict__ out, int N) {
    int n = blockIdx.x * blockDim.x + threadIdx.x;
    if (n >= N) return;
    float acc = z[n];
    int j = rp[n], jend = rp[n + 1];
    for (; j + 4 <= jend; j += 4) {
        float a0 = z[csrc[j]];
        float a1 = z[csrc[j + 1]];
        float a2 = z[csrc[j + 2]];
        float a3 = z[csrc[j + 3]];
        acc += (a0 + a1) + (a2 + a3);
    }
    for (; j < jend; ++j) acc += z[csrc[j]];
    out[n] = dis[n] * acc + b2[0];
}

extern "C" void kernel_launch(void* const* d_in, const int* in_sizes, int n_in,
                              void* d_out, int out_size, void* d_ws, size_t ws_size,
                              hipStream_t stream) {
    const float* x  = (const float*)d_in[0];
    const int*   ei = (const int*)d_in[1];
    const float* W1 = (const float*)d_in[2];
    const float* b1 = (const float*)d_in[3];
    const float* W2 = (const float*)d_in[4];
    const float* b2 = (const float*)d_in[5];
    float* out = (float*)d_out;

    const int N = in_sizes[0] / IN_CH;            // 50000
    const int E = in_sizes[1] / 2;                // 800000
    const int nbm = (N + 127) / 128;              // 391
    const int M2 = nbm * 128;                     // 50048
    const int NB = (N + SCAN_BLK - 1) / SCAN_BLK; // 49 (<= 64 for k_write)
    const int DEGB  = (E + 255) / 256;            // 3125
    const int FILLB = ((DEGB + 7) / 8) * 8;       // 3128, %8==0 keeps XCD swizzle clean

    char* ws = (char*)d_ws;
    size_t off = 0;
    auto alloc = [&](size_t bytes) {
        char* p = ws + off;
        off += (bytes + 255) & ~(size_t)255;
        return p;
    };
    _Float16* y   = (_Float16*)alloc((size_t)M2 * 512 * sizeof(_Float16)); // 51.25 MB
    _Float16* W1t = (_Float16*)alloc((size_t)512 * 512 * sizeof(_Float16));
    int*   deg    = (int*)alloc((size_t)N * sizeof(int));
    float* dis    = (float*)alloc((size_t)N * sizeof(float));
    int*   rp     = (int*)alloc((size_t)(N + 1) * sizeof(int));
    int*   cursor = (int*)alloc((size_t)N * sizeof(int));
    int*   csrc   = (int*)alloc((size_t)E * sizeof(int));
    float* z      = (float*)alloc((size_t)N * sizeof(float));
    int*   bsum   = (int*)alloc((size_t)64 * sizeof(int));

    hipMemsetAsync(deg, 0, (size_t)N * sizeof(int), stream);

    k_merged1<<<256 + DEGB, 256, 0, stream>>>(W1, W1t, ei + E, deg, E, N);
    k_psum<<<NB, SCAN_BLK, 0, stream>>>(deg, bsum, N);
    k_write<<<NB, SCAN_BLK, 0, stream>>>(deg, bsum, rp, dis, cursor, N);
    k_merged2<<<FILLB + nbm * 4, 256, 0, stream>>>(x, W1t, y, N, nbm, FILLB,
                                                   ei, rp, cursor, csrc, E, N);
    k_agg<<<(N + 3) / 4, 256, 0, stream>>>(y, dis, rp, csrc, b1, W2, z, N);
    k_out<<<(N + 255) / 256, 256, 0, stream>>>(z, dis, rp, csrc, b2, out, N);
}